// Round 1
// 393.412 us; speedup vs baseline: 1.0059x; 1.0059x over previous
//
#include <hip/hip_runtime.h>
#include <hip/hip_bf16.h>
#include <math.h>

// Problem: B=16, N=1024, D=1024, H=8, HD=128
#define BN 1024
#define DD 1024
#define NB 16
#define NH 8
#define HDIM 128

typedef __attribute__((ext_vector_type(8))) short bf16x8;
typedef __attribute__((ext_vector_type(4))) float f32x4;
typedef __attribute__((ext_vector_type(4))) unsigned short ushort4v;

#define DEV __device__ __forceinline__

DEV unsigned short f2bf(float f) {
  unsigned u = __float_as_uint(f);
  u = (u + 0x7fffu + ((u >> 16) & 1u)) >> 16;  // RNE
  return (unsigned short)u;
}

DEV f32x4 mfma16(bf16x8 a, bf16x8 b, f32x4 c) {
  return __builtin_amdgcn_mfma_f32_16x16x32_bf16(a, b, c, 0, 0, 0);
}

// async global->LDS, 16B per lane. LDS dest = wave-uniform base + lane*16.
DEV void async16(const unsigned short* g, unsigned short* l) {
  __builtin_amdgcn_global_load_lds(
      (const __attribute__((address_space(1))) unsigned short*)g,
      (__attribute__((address_space(3))) unsigned short*)l, 16, 0, 0);
}

// ---------------------------------------------------------------------------
// K0 (fused prep): conv_x | transpose_qkv | transpose_fc, branched on blockIdx
// ---------------------------------------------------------------------------
__global__ __launch_bounds__(256) void prep_kernel(
    const float* __restrict__ x, const float* __restrict__ Wq,
    const float* __restrict__ Wk, const float* __restrict__ Wv,
    const float* __restrict__ Wfc, unsigned short* __restrict__ x_bf,
    unsigned short* __restrict__ wqkvT, unsigned short* __restrict__ wfcT) {
  __shared__ float tile[32][33];
  const int bx = blockIdx.x, tid = threadIdx.x;
  if (bx < 16384) {
    int i = bx * 256 + tid;
    const float4* p = (const float4*)x;
    float4 v = p[i];
    ushort4v o;
    o[0] = f2bf(v.x); o[1] = f2bf(v.y); o[2] = f2bf(v.z); o[3] = f2bf(v.w);
    *(ushort4v*)(x_bf + (size_t)i * 4) = o;
    return;
  }
  const int tx = tid & 31, ty = tid >> 5;
  if (bx < 19456) {
    int idx = bx - 16384;
    int k0 = (idx & 31) * 32, e0 = ((idx >> 5) & 3) * 32, z = idx >> 7;
    int which = z >> 3, h = z & 7;
    const float* in = (which == 0 ? Wq : (which == 1 ? Wk : Wv)) + (size_t)h * DD * HDIM;
#pragma unroll
    for (int i = 0; i < 4; ++i)
      tile[ty + i * 8][tx] = in[(size_t)(k0 + ty + i * 8) * HDIM + e0 + tx];
    __syncthreads();
    int rowbase = which * 1024 + h * 128 + e0;
#pragma unroll
    for (int i = 0; i < 4; ++i)
      wqkvT[(size_t)(rowbase + ty + i * 8) * DD + k0 + tx] = f2bf(tile[tx][ty + i * 8]);
  } else {
    int idx = bx - 19456;
    int d0 = (idx & 31) * 32, c0 = (idx >> 5) * 32;
#pragma unroll
    for (int i = 0; i < 4; ++i)
      tile[ty + i * 8][tx] = Wfc[(size_t)(d0 + ty + i * 8) * DD + c0 + tx];
    __syncthreads();
#pragma unroll
    for (int i = 0; i < 4; ++i)
      wfcT[(size_t)(c0 + ty + i * 8) * DD + d0 + tx] = f2bf(tile[tx][ty + i * 8]);
  }
}

// ---------------------------------------------------------------------------
// GEMM v2: 256x256 tile, BK=64, 512 threads (8 waves, 2Mx4N INTERLEAVED wave
// mapping), 8-phase counted-vmcnt schedule (T3+T4) + setprio (T5).
//
// Wave (wr=w>>2, wc=w&3) owns rows {wr*16 + mt*32} mt=0..7 and cols
// {wc*16 + nt*64} nt=0..3 -- interleaving means phase p's fragments come
// from the SAME staged 64-row half for every wave, so per-half-tile counted
// vmcnt waits are workgroup-uniform.
//
// Stage half-tiles per K-tile: L1=A[0:128) L2=B[0:128) L3=B[128:256)
// L4=A[128:256), 2 global_load_lds each, issued one per phase (P1..P4).
// Consumption: P1 needs L1,L2(t); P2 needs L3(t); P3 needs L4(t); P4 none.
// Queue-derived waits (never 0): vmcnt(4) at P1, P2, P4; none at P3.
// In-flight: 4-8 insts (2-4 half-tiles) across barriers.
//
// LDS: [2][256][64] bf16 per operand = 128 KB, row-rotation swizzle
// LDS[r][c] = G[r][(c-r)&7] (pre-swizzled global src, linear gl_lds dest;
// read chunk (ks*4+quad+row)&7) -- same scheme the 128^2 kernel measured at
// 0 bank conflicts. 1 block/CU (LDS-bound), 2 waves/SIMD.
// ---------------------------------------------------------------------------
template <int MODE>
__global__ __launch_bounds__(512, 2) void gemm256_kernel(
    const unsigned short* __restrict__ A, const unsigned short* __restrict__ Bt,
    const float* __restrict__ bias0, const float* __restrict__ bias1,
    const float* __restrict__ bias2, unsigned short* __restrict__ out0,
    unsigned short* __restrict__ out1, unsigned short* __restrict__ out2,
    float* __restrict__ outf) {
  __shared__ unsigned short As[2][256 * 64];
  __shared__ unsigned short Bs[2][256 * 64];
  const int tid = threadIdx.x;
  const int w = tid >> 6, lane = tid & 63, quad = lane >> 4, l15 = lane & 15;
  const int wr = w >> 2, wc = w & 3;

  // XCD-aware bijective swizzle (nwg % 8 == 0 for both modes)
  constexpr int NBN = (MODE == 0) ? 12 : 4;   // n-blocks
  constexpr int CPX = (MODE == 0) ? 96 : 32;  // blocks per XCD
  const int bid = blockIdx.x;
  const int swz = (bid & 7) * CPX + (bid >> 3);
  const int mblk = swz / NBN, nblk = swz - mblk * NBN;
  const int m0 = mblk << 8, n0 = nblk << 8;

  // staging addresses: thread t covers row (t>>3) of each 64-row group,
  // global chunk ((t&7) - row) & 7  (rotation pre-swizzle)
  const int srow = tid >> 3;
  const int gch = ((tid & 7) - srow) & 7;
  const unsigned short* ag = A + (size_t)(m0 + srow) * 1024 + gch * 8;
  const unsigned short* bg = Bt + (size_t)(n0 + srow) * 1024 + gch * 8;
  const int wbase = w * 512;  // elems: wave-uniform LDS base within 64-row group

  // fragment read column rotation: chunk = (ks*4 + quad + row)&7, row%8 == l15%8
  const int sl0 = ((quad + l15) & 7) * 8;
  const int sl1 = ((quad + l15 + 4) & 7) * 8;

  f32x4 acc[8][4] = {};
  bf16x8 af[4][2];   // A frags of current m-half (overwritten P1 -> P3)
  bf16x8 bfr[4][2];  // B frags: [0..1]=n-lo (P1), [2..3]=n-hi (P2), both live

  // ---- prologue: stage tile 0 (L1,L2,L3,L4), force L1,L2 complete ----
  async16(ag, &As[0][0] + wbase);
  async16(ag + 64 * 1024, &As[0][64 * 64] + wbase);
  async16(bg, &Bs[0][0] + wbase);
  async16(bg + 64 * 1024, &Bs[0][64 * 64] + wbase);
  async16(bg + 128 * 1024, &Bs[0][128 * 64] + wbase);
  async16(bg + 192 * 1024, &Bs[0][192 * 64] + wbase);
  async16(ag + 128 * 1024, &As[0][128 * 64] + wbase);
  async16(ag + 192 * 1024, &As[0][192 * 64] + wbase);
  asm volatile("s_waitcnt vmcnt(4)" ::: "memory");
  __builtin_amdgcn_s_barrier();

  for (int t = 0; t < 16; ++t) {
    const int cur = t & 1;
    const unsigned short* ac = &As[cur][0];
    const unsigned short* bc = &Bs[cur][0];
    unsigned short* an = &As[cur ^ 1][0];
    unsigned short* bn = &Bs[cur ^ 1][0];
    const int kb2 = ((t + 1) & 15) * 64;  // next tile's k (wraps: harmless re-read)

    // ---- P1: read A-lo + B-lo; stage L1(t+1)=A-lo; vmcnt(4) [forces L3(t)]
#pragma unroll
    for (int mt = 0; mt < 4; ++mt) {
      const unsigned short* rp = ac + (wr * 16 + mt * 32 + l15) * 64;
      af[mt][0] = *(const bf16x8*)(rp + sl0);
      af[mt][1] = *(const bf16x8*)(rp + sl1);
    }
#pragma unroll
    for (int nt = 0; nt < 2; ++nt) {
      const unsigned short* rp = bc + (wc * 16 + nt * 64 + l15) * 64;
      bfr[nt][0] = *(const bf16x8*)(rp + sl0);
      bfr[nt][1] = *(const bf16x8*)(rp + sl1);
    }
    async16(ag + kb2, an + wbase);
    async16(ag + kb2 + 64 * 1024, an + 64 * 64 + wbase);
    asm volatile("s_waitcnt vmcnt(4)" ::: "memory");
    __builtin_amdgcn_s_barrier();
    asm volatile("s_waitcnt lgkmcnt(0)" ::: "memory");
    __builtin_amdgcn_s_setprio(1);
#pragma unroll
    for (int mt = 0; mt < 4; ++mt)
#pragma unroll
      for (int nt = 0; nt < 2; ++nt) {
        acc[mt][nt] = mfma16(af[mt][0], bfr[nt][0], acc[mt][nt]);
        acc[mt][nt] = mfma16(af[mt][1], bfr[nt][1], acc[mt][nt]);
      }
    __builtin_amdgcn_s_setprio(0);
    __builtin_amdgcn_s_barrier();

    // ---- P2: read B-hi; stage L2(t+1)=B-lo; vmcnt(4) [forces L4(t)]
#pragma unroll
    for (int nt = 0; nt < 2; ++nt) {
      const unsigned short* rp = bc + (wc * 16 + 128 + nt * 64 + l15) * 64;
      bfr[2 + nt][0] = *(const bf16x8*)(rp + sl0);
      bfr[2 + nt][1] = *(const bf16x8*)(rp + sl1);
    }
    async16(bg + kb2, bn + wbase);
    async16(bg + kb2 + 64 * 1024, bn + 64 * 64 + wbase);
    asm volatile("s_waitcnt vmcnt(4)" ::: "memory");
    __builtin_amdgcn_s_barrier();
    asm volatile("s_waitcnt lgkmcnt(0)" ::: "memory");
    __builtin_amdgcn_s_setprio(1);
#pragma unroll
    for (int mt = 0; mt < 4; ++mt)
#pragma unroll
      for (int nt = 0; nt < 2; ++nt) {
        acc[mt][2 + nt] = mfma16(af[mt][0], bfr[2 + nt][0], acc[mt][2 + nt]);
        acc[mt][2 + nt] = mfma16(af[mt][1], bfr[2 + nt][1], acc[mt][2 + nt]);
      }
    __builtin_amdgcn_s_setprio(0);
    __builtin_amdgcn_s_barrier();

    // ---- P3: read A-hi (overwrite af); stage L3(t+1)=B-hi; no vmcnt
#pragma unroll
    for (int mt = 0; mt < 4; ++mt) {
      const unsigned short* rp = ac + (wr * 16 + 128 + mt * 32 + l15) * 64;
      af[mt][0] = *(const bf16x8*)(rp + sl0);
      af[mt][1] = *(const bf16x8*)(rp + sl1);
    }
    async16(bg + kb2 + 128 * 1024, bn + 128 * 64 + wbase);
    async16(bg + kb2 + 192 * 1024, bn + 192 * 64 + wbase);
    __builtin_amdgcn_s_barrier();
    asm volatile("s_waitcnt lgkmcnt(0)" ::: "memory");
    __builtin_amdgcn_s_setprio(1);
#pragma unroll
    for (int mt = 0; mt < 4; ++mt)
#pragma unroll
      for (int nt = 0; nt < 2; ++nt) {
        acc[4 + mt][2 + nt] = mfma16(af[mt][0], bfr[2 + nt][0], acc[4 + mt][2 + nt]);
        acc[4 + mt][2 + nt] = mfma16(af[mt][1], bfr[2 + nt][1], acc[4 + mt][2 + nt]);
      }
    __builtin_amdgcn_s_setprio(0);
    __builtin_amdgcn_s_barrier();

    // ---- P4: no new reads; stage L4(t+1)=A-hi; vmcnt(4) [forces L1,L2(t+1)]
    async16(ag + kb2 + 128 * 1024, an + 128 * 64 + wbase);
    async16(ag + kb2 + 192 * 1024, an + 192 * 64 + wbase);
    asm volatile("s_waitcnt vmcnt(4)" ::: "memory");
    __builtin_amdgcn_s_barrier();
    __builtin_amdgcn_s_setprio(1);
#pragma unroll
    for (int mt = 0; mt < 4; ++mt)
#pragma unroll
      for (int nt = 0; nt < 2; ++nt) {
        acc[4 + mt][nt] = mfma16(af[mt][0], bfr[nt][0], acc[4 + mt][nt]);
        acc[4 + mt][nt] = mfma16(af[mt][1], bfr[nt][1], acc[4 + mt][nt]);
      }
    __builtin_amdgcn_s_setprio(0);
    __builtin_amdgcn_s_barrier();
  }

  // ---- epilogue ----
  if constexpr (MODE == 0) {
    const int seg = n0 >> 10;  // 0=q 1=k 2=v (256-tile never straddles segs)
    const float* bp = (seg == 0) ? bias0 : (seg == 1 ? bias1 : bias2);
#pragma unroll
    for (int ai = 0; ai < 8; ++ai) {
      int mb = m0 + wr * 16 + ai * 32 + quad * 4;
      int bb = mb >> 10, nn = mb & 1023;
#pragma unroll
      for (int nt = 0; nt < 4; ++nt) {
        int c = n0 + wc * 16 + nt * 64 + l15;
        int cc = c & 1023;
        int h = cc >> 7, e = cc & 127;
        float bias = bp[cc];
        if (seg == 2) {
          ushort4v pv;
#pragma unroll
          for (int r = 0; r < 4; ++r) pv[r] = f2bf(acc[ai][nt][r] + bias);
          *(ushort4v*)(out2 + ((size_t)(bb * NH + h) * HDIM + e) * BN + nn) = pv;
        } else {
          unsigned short* op = (seg == 0) ? out0 : out1;
#pragma unroll
          for (int r = 0; r < 4; ++r)
            op[(((size_t)bb * NH + h) * BN + (nn + r)) * HDIM + e] =
                f2bf(acc[ai][nt][r] + bias);
        }
      }
    }
  } else {
#pragma unroll
    for (int ai = 0; ai < 8; ++ai) {
      int mb = m0 + wr * 16 + ai * 32 + quad * 4;
#pragma unroll
      for (int nt = 0; nt < 4; ++nt) {
        int c = n0 + wc * 16 + nt * 64 + l15;
        float bias = bias0[c];
#pragma unroll
        for (int r = 0; r < 4; ++r)
          outf[(size_t)(mb + r) * DD + c] = acc[ai][nt][r] + bias;
      }
    }
  }
}

// ---------------------------------------------------------------------------
// K4: flash attention v6 — 2x2 wave split to kill LDS-read redundancy.
// (unchanged this round)
// ---------------------------------------------------------------------------
__global__ __launch_bounds__(256, 2) void flash_attn_kernel(
    const unsigned short* __restrict__ Q, const unsigned short* __restrict__ Kk,
    const unsigned short* __restrict__ Vt, const int* __restrict__ xmask,
    unsigned short* __restrict__ O) {
  __shared__ unsigned short k_s[64 * 128];       // 16 KB, swizzled
  __shared__ unsigned short v_s[2][128 * 64];    // 32 KB, swizzled, dbuf
  __shared__ unsigned short p_s[128 * 72];       // 18 KB, padded (shared P)
  __shared__ float l_s[2][128];                  // 1 KB

  const float CL2E = 0.08838834764831845f * 1.44269504088896f;  // SCALE*log2(e)

  const int tid = threadIdx.x;
  const int w = tid >> 6, lane = tid & 63, quad = lane >> 4, l15 = lane & 15;
  const int wq = w >> 1, wk = w & 1;             // we == wk
  const int lin = blockIdx.x;
  const int bh = lin & 127, qb = lin >> 7;
  const int b = bh >> 3, h = bh & 7;
  const int q0 = qb * 128;
  const unsigned short* qp = Q + ((size_t)bh * BN + q0) * HDIM;
  const unsigned short* kp = Kk + (size_t)bh * BN * HDIM;
  const unsigned short* vp = Vt + (size_t)bh * HDIM * BN;
  const int* xm_b = xmask + b * BN;

  // Q fragments (A-layout) for 64 rows: row = wq*64 + mt*16 + l15
  bf16x8 qf[4][4];
#pragma unroll
  for (int mt = 0; mt < 4; ++mt)
#pragma unroll
    for (int ks = 0; ks < 4; ++ks)
      qf[mt][ks] = *(const bf16x8*)(qp + (wq * 64 + mt * 16 + l15) * HDIM + ks * 32 + quad * 8);

  // row masks packed: bit (mt*4+r) for row wq*64 + mt*16 + quad*4 + r
  int rowm_bits = 0;
#pragma unroll
  for (int mt = 0; mt < 4; ++mt)
#pragma unroll
    for (int r = 0; r < 4; ++r)
      rowm_bits |= (xm_b[q0 + wq * 64 + mt * 16 + quad * 4 + r] ? 1 : 0) << (mt * 4 + r);

  // staging lane decomposition (same swizzles as R5: measured conflict-free)
  const int krow = lane >> 4;
  const int vrow = lane >> 3;
  const int vch = ((lane & 7) - vrow) & 7;

  float l_lane[4][4] = {};
  f32x4 o_acc[4][4] = {};

  // pre-issue tile 0
#pragma unroll
  for (int i = 0; i < 4; ++i) {
    int rmod = i * 4 + krow;
    int g = ((lane & 15) - rmod) & 15;
    async16(kp + (size_t)(w * 16 + rmod) * HDIM + g * 8, k_s + (w * 16 + i * 4) * 128);
    int e = w * 32 + i * 8 + vrow;
    async16(vp + (size_t)e * BN + vch * 8, v_s[0] + (w * 32 + i * 8) * 64);
  }

  for (int it = 0; it < 16; ++it) {
    const int kb = it * 64;
    int cm0 = xm_b[kb + wk * 32 + l15];
    int cm1 = xm_b[kb + wk * 32 + 16 + l15];
    __syncthreads();  // sync_a: K/V tiles arrived; prev p_s reads done

    // S slice = Q[wq-half] K^T[wk-half]  (64q x 32k)
    f32x4 s[4][2] = {};
#pragma unroll
    for (int ks = 0; ks < 4; ++ks) {
      const int sl = ((ks * 4 + quad + l15) & 15) * 8;
      bf16x8 b0 = *(const bf16x8*)(k_s + (wk * 32 + l15) * 128 + sl);
      bf16x8 b1 = *(const bf16x8*)(k_s + (wk * 32 + 16 + l15) * 128 + sl);
#pragma unroll
      for (int mt = 0; mt < 4; ++mt) {
        s[mt][0] = mfma16(qf[mt][ks], b0, s[mt][0]);
        s[mt][1] = mfma16(qf[mt][ks], b1, s[mt][1]);
      }
    }

    // fixed-max softmax -> shared p_s, accumulate partial l per lane
#pragma unroll
    for (int mt = 0; mt < 4; ++mt)
#pragma unroll
      for (int nt = 0; nt < 2; ++nt) {
        int cmv = nt ? cm1 : cm0;
#pragma unroll
        for (int r = 0; r < 4; ++r) {
          float xs = s[mt][nt][r] * CL2E;
          float t = cmv ? xs : -60.0f;
          int rb = (rowm_bits >> (mt * 4 + r)) & 1;
          float e2 = rb ? t : 0.0f;
          float p = __builtin_amdgcn_exp2f(e2);
          l_lane[mt][r] += p;
          p_s[(wq * 64 + mt * 16 + quad * 4 + r) * 72 + wk * 32 + nt * 16 + l15] = f2bf(p);
        }
      }

    __syncthreads();  // sync_b: p_s complete; all k_s reads done

    // prefetch next K/V (wrapped on last iter; harmless re-read)
    {
      const int kn = (kb + 64) & (BN - 1);
      unsigned short* vb_next = v_s[(it + 1) & 1];
#pragma unroll
      for (int i = 0; i < 4; ++i) {
        int rmod = i * 4 + krow;
        int g = ((lane & 15) - rmod) & 15;
        async16(kp + (size_t)(kn + w * 16 + rmod) * HDIM + g * 8,
                k_s + (w * 16 + i * 4) * 128);
        int e = w * 32 + i * 8 + vrow;
        async16(vp + (size_t)e * BN + kn + vch * 8, vb_next + (w * 32 + i * 8) * 64);
      }
    }

    // O slice += P[wq-half][64k] V[64k][we-half]  (64q x 64e)
    const unsigned short* vb = v_s[it & 1];
#pragma unroll
    for (int ks2 = 0; ks2 < 2; ++ks2) {
      const int sl = ((ks2 * 4 + quad + l15) & 7) * 8;
      bf16x8 pa[4];
#pragma unroll
      for (int mt = 0; mt < 4; ++mt)
        pa[mt] = *(const bf16x8*)(p_s + (wq * 64 + mt * 16 + l15) * 72 + ks2 * 32 + quad * 8);
#pragma unroll
      for (int et = 0; et < 4; ++et) {
        bf16x8 bv = *(const bf16x8*)(vb + (wk * 64 + et * 16 + l15) * 64 + sl);
#pragma unroll
        for (int mt = 0; mt < 4; ++mt)
          o_acc[mt][et] = mfma16(pa[mt], bv, o_acc[mt][et]);
      }
    }
  }

  // merge partial l across the two k-half waves via LDS
#pragma unroll
  for (int mt = 0; mt < 4; ++mt)
#pragma unroll
    for (int r = 0; r < 4; ++r) {
      float l = l_lane[mt][r];
#pragma unroll
      for (int off = 1; off < 16; off <<= 1) l += __shfl_xor(l, off, 64);
      if (l15 == 0) l_s[wk][wq * 64 + mt * 16 + quad * 4 + r] = l;
    }
  __syncthreads();

  // epilogue: O/l, store slice [64q x 64e]
#pragma unroll
  for (int mt = 0; mt < 4; ++mt)
#pragma unroll
    for (int r = 0; r < 4; ++r) {
      int rl = wq * 64 + mt * 16 + quad * 4 + r;
      float inv = 1.0f / (l_s[0][rl] + l_s[1][rl]);
      int row = q0 + rl;
#pragma unroll
      for (int et = 0; et < 4; ++et) {
        int col = h * HDIM + wk * 64 + et * 16 + l15;
        O[((size_t)b * BN + row) * DD + col] = f2bf(o_acc[mt][et][r] * inv);
      }
    }
}

// ---------------------------------------------------------------------------
// Workspace layout (bytes): total ~168 MB
//   x_bf @0 33554432 | wqkvT @33554432 6291456 | wfcT @39845888 2097152
//   q_bf @41943040 | k_bf @75497472 | vT_bf @109051904 | o_bf @142606336 (each 33554432)
// ---------------------------------------------------------------------------
extern "C" void kernel_launch(void* const* d_in, const int* in_sizes, int n_in,
                              void* d_out, int out_size, void* d_ws, size_t ws_size,
                              hipStream_t stream) {
  const float* x = (const float*)d_in[0];
  const int* xmask = (const int*)d_in[1];
  const float* Wq = (const float*)d_in[2];
  const float* bq = (const float*)d_in[3];
  const float* Wk = (const float*)d_in[4];
  const float* bk = (const float*)d_in[5];
  const float* Wv = (const float*)d_in[6];
  const float* bv = (const float*)d_in[7];
  const float* Wfc = (const float*)d_in[8];
  const float* bfc = (const float*)d_in[9];
  float* out = (float*)d_out;

  char* ws = (char*)d_ws;
  unsigned short* x_bf  = (unsigned short*)(ws);
  unsigned short* wqkvT = (unsigned short*)(ws + 33554432);
  unsigned short* wfcT  = (unsigned short*)(ws + 39845888);
  unsigned short* q_bf  = (unsigned short*)(ws + 41943040);
  unsigned short* k_bf  = (unsigned short*)(ws + 75497472);
  unsigned short* vT_bf = (unsigned short*)(ws + 109051904);
  unsigned short* o_bf  = (unsigned short*)(ws + 142606336);

  prep_kernel<<<dim3(20480), dim3(256), 0, stream>>>(x, Wq, Wk, Wv, Wfc, x_bf, wqkvT, wfcT);

  // QKV: M=16384, N=3072 -> 64 x 12 = 768 blocks (exactly 3 waves of 256 CUs)
  gemm256_kernel<0><<<dim3(768), dim3(512), 0, stream>>>(
      x_bf, wqkvT, bq, bk, bv, q_bf, k_bf, vT_bf, nullptr);

  flash_attn_kernel<<<dim3(1024), dim3(256), 0, stream>>>(q_bf, k_bf, vT_bf, xmask, o_bf);

  // FC: M=16384, N=1024 -> 64 x 4 = 256 blocks (exactly 1 per CU)
  gemm256_kernel<1><<<dim3(256), dim3(512), 0, stream>>>(
      o_bf, wfcT, bfc, nullptr, nullptr, nullptr, nullptr, nullptr, out);
}